// Round 2
// baseline (854.399 us; speedup 1.0000x reference)
//
#include <hip/hip_runtime.h>
#include <math.h>

#define HH 512
#define WW 512
#define NBATCH 64
#define TW 64
#define TH 16
#define NTILES (NBATCH * 8 * 32)  // 16384
#define NTHR 256

#define XT_H (TH + 4)  // 20  (halo 2)
#define XT_W (TW + 4)  // 68
#define ZT_H (TH + 2)  // 18
#define ZT_W (TW + 2)  // 66
#define X1_H (TH + 2)  // 18  (halo 1)
#define X1_W (TW + 2)  // 66

// rational 'A': P(x)/(1+|Q(x)|), deg P=5, deg Q=4 no constant term
__device__ __forceinline__ float ratf(float v, const float* A, const float* B) {
  float p = fmaf(v, A[5], A[4]);
  p = fmaf(v, p, A[3]);
  p = fmaf(v, p, A[2]);
  p = fmaf(v, p, A[1]);
  p = fmaf(v, p, A[0]);
  float q = fmaf(v, B[3], B[2]);
  q = fmaf(v, q, B[1]);
  q = fmaf(v, q, B[0]);
  q *= v;
  float den = 1.0f + fabsf(q);
  return p * __builtin_amdgcn_rcpf(den);
}

__device__ __forceinline__ void block_reduce6_store(float s[6], float* __restrict__ dst) {
  __shared__ float red[4][6];
#pragma unroll
  for (int k = 0; k < 6; ++k) {
    float v = s[k];
#pragma unroll
    for (int off = 32; off; off >>= 1) v += __shfl_down(v, off, 64);
    s[k] = v;
  }
  int lane = threadIdx.x & 63, wv = threadIdx.x >> 6;
  if (lane == 0) {
#pragma unroll
    for (int k = 0; k < 6; ++k) red[wv][k] = s[k];
  }
  __syncthreads();
  if (threadIdx.x < 6) {
    dst[threadIdx.x] = red[0][threadIdx.x] + red[1][threadIdx.x] + red[2][threadIdx.x] + red[3][threadIdx.x];
  }
}

// ---------------- kernel 1: conv1 stats ----------------
__global__ __launch_bounds__(NTHR) void k_stats1(const float* __restrict__ x,
                                                 const float* __restrict__ w1,
                                                 float* __restrict__ partials) {
  __shared__ float xs[3][X1_H][X1_W];
  int bid = blockIdx.x;
  int tx = bid & 7, ty = (bid >> 3) & 31, b = bid >> 8;
  int h0 = ty * TH, w0 = tx * TW;

  const int NE = 3 * X1_H * X1_W;
  for (int i = threadIdx.x; i < NE; i += NTHR) {
    int c = i / (X1_H * X1_W);
    int rem = i - c * (X1_H * X1_W);
    int r = rem / X1_W, cc = rem - r * X1_W;
    int gh = h0 - 1 + r, gw = w0 - 1 + cc;
    float v = 0.f;
    if ((unsigned)gh < HH && (unsigned)gw < WW)
      v = x[(((size_t)b * 3 + c) * HH + gh) * WW + gw];
    xs[c][r][cc] = v;
  }
  float wr[3][3][3][3];
#pragma unroll
  for (int o = 0; o < 3; ++o)
#pragma unroll
    for (int ci = 0; ci < 3; ++ci)
#pragma unroll
      for (int ky = 0; ky < 3; ++ky)
#pragma unroll
        for (int kx = 0; kx < 3; ++kx)
          wr[o][ci][ky][kx] = w1[((o * 3 + ci) * 3 + ky) * 3 + kx];
  __syncthreads();

  int cc = threadIdx.x & 63;
  int rr0 = (threadIdx.x >> 6) * 4;  // 4-row strip
  float acc[4][3] = {};
#pragma unroll
  for (int ci = 0; ci < 3; ++ci)
#pragma unroll
    for (int kx = 0; kx < 3; ++kx) {
      float v[6];
#pragma unroll
      for (int i = 0; i < 6; ++i) v[i] = xs[ci][rr0 + i][cc + kx];
#pragma unroll
      for (int o = 0; o < 4; ++o)
#pragma unroll
        for (int ky = 0; ky < 3; ++ky) {
          float vv = v[o + ky];
#pragma unroll
          for (int co = 0; co < 3; ++co) acc[o][co] = fmaf(wr[co][ci][ky][kx], vv, acc[o][co]);
        }
    }
  float s[6] = {0.f, 0.f, 0.f, 0.f, 0.f, 0.f};
#pragma unroll
  for (int o = 0; o < 4; ++o)
#pragma unroll
    for (int co = 0; co < 3; ++co) {
      float y = acc[o][co];
      s[co] += y;
      s[3 + co] += y * y;
    }
  block_reduce6_store(s, partials + (size_t)bid * 6);
}

// ---------------- reduce partials -> scale/shift (6 floats) ----------------
__global__ __launch_bounds__(256) void k_reduce(const float* __restrict__ partials,
                                                const float* __restrict__ gamma,
                                                const float* __restrict__ beta,
                                                float* __restrict__ out6) {
  double s[6] = {0, 0, 0, 0, 0, 0};
  for (int j = threadIdx.x; j < NTILES; j += 256) {
    const float* p = partials + (size_t)j * 6;
#pragma unroll
    for (int k = 0; k < 6; ++k) s[k] += (double)p[k];
  }
  __shared__ double red[256];
  __shared__ double tot[6];
  for (int k = 0; k < 6; ++k) {
    red[threadIdx.x] = s[k];
    __syncthreads();
    for (int off = 128; off; off >>= 1) {
      if (threadIdx.x < off) red[threadIdx.x] += red[threadIdx.x + off];
      __syncthreads();
    }
    if (threadIdx.x == 0) tot[k] = red[0];
    __syncthreads();
  }
  if (threadIdx.x < 3) {
    int c = threadIdx.x;
    double N = 16777216.0;  // 64*512*512
    double mean = tot[c] / N;
    double var = tot[3 + c] / N - mean * mean;
    double sc = (double)gamma[c] / sqrt(var + 1e-5);
    double sh = (double)beta[c] - mean * sc;
    out6[c] = (float)sc;
    out6[3 + c] = (float)sh;
  }
}

// ---------------- fused conv1+bn1+rat+conv2 (+bn2+res+rat or stats) --------
// FINAL=false: write per-block conv2 stats partials to dst.
// FINAL=true : apply bn2 (hdr[6..11]) + residual + rational, write output to dst.
template <bool FINAL>
__global__ __launch_bounds__(NTHR) void k_fused(const float* __restrict__ x,
                                                const float* __restrict__ w1,
                                                const float* __restrict__ w2,
                                                const float* __restrict__ hdr,
                                                const float* __restrict__ ar, const float* __restrict__ br,
                                                const float* __restrict__ ag, const float* __restrict__ bg,
                                                const float* __restrict__ ab_, const float* __restrict__ bb,
                                                float* __restrict__ dst) {
  __shared__ float xs[3][XT_H][XT_W];
  __shared__ float zs[3][ZT_H][ZT_W];
  int bid = blockIdx.x;
  int tx = bid & 7, ty = (bid >> 3) & 31, b = bid >> 8;
  int h0 = ty * TH, w0 = tx * TW;

  const int NE = 3 * XT_H * XT_W;
  for (int i = threadIdx.x; i < NE; i += NTHR) {
    int c = i / (XT_H * XT_W);
    int rem = i - c * (XT_H * XT_W);
    int r = rem / XT_W, cc = rem - r * XT_W;
    int gh = h0 - 2 + r, gw = w0 - 2 + cc;
    float v = 0.f;
    if ((unsigned)gh < HH && (unsigned)gw < WW)
      v = x[(((size_t)b * 3 + c) * HH + gh) * WW + gw];
    xs[c][r][cc] = v;
  }

  float scale1[3], shift1[3];
#pragma unroll
  for (int c = 0; c < 3; ++c) {
    scale1[c] = hdr[c];
    shift1[c] = hdr[3 + c];
  }
  float A[3][6], Bq[3][4];
#pragma unroll
  for (int i = 0; i < 6; ++i) { A[0][i] = ar[i]; A[1][i] = ag[i]; A[2][i] = ab_[i]; }
#pragma unroll
  for (int i = 0; i < 4; ++i) { Bq[0][i] = br[i]; Bq[1][i] = bg[i]; Bq[2][i] = bb[i]; }

  float wr[3][3][3][3];
#pragma unroll
  for (int o = 0; o < 3; ++o)
#pragma unroll
    for (int ci = 0; ci < 3; ++ci)
#pragma unroll
      for (int ky = 0; ky < 3; ++ky)
#pragma unroll
        for (int kx = 0; kx < 3; ++kx)
          wr[o][ci][ky][kx] = w1[((o * 3 + ci) * 3 + ky) * 3 + kx];
  __syncthreads();

  // z = rational(bn1(conv1(x))) over the halo-1 tile
  for (int i = threadIdx.x; i < ZT_H * ZT_W; i += NTHR) {
    int r = i / ZT_W, cc = i - r * ZT_W;
    int gh = h0 - 1 + r, gw = w0 - 1 + cc;
    float z0 = 0.f, z1 = 0.f, z2 = 0.f;
    if ((unsigned)gh < HH && (unsigned)gw < WW) {
      float a0 = 0.f, a1 = 0.f, a2 = 0.f;
#pragma unroll
      for (int ci = 0; ci < 3; ++ci)
#pragma unroll
        for (int ky = 0; ky < 3; ++ky)
#pragma unroll
          for (int kx = 0; kx < 3; ++kx) {
            float v = xs[ci][r + ky][cc + kx];
            a0 = fmaf(wr[0][ci][ky][kx], v, a0);
            a1 = fmaf(wr[1][ci][ky][kx], v, a1);
            a2 = fmaf(wr[2][ci][ky][kx], v, a2);
          }
      z0 = ratf(fmaf(a0, scale1[0], shift1[0]), A[0], Bq[0]);
      z1 = ratf(fmaf(a1, scale1[1], shift1[1]), A[1], Bq[1]);
      z2 = ratf(fmaf(a2, scale1[2], shift1[2]), A[2], Bq[2]);
    }
    zs[0][r][cc] = z0;
    zs[1][r][cc] = z1;
    zs[2][r][cc] = z2;
  }

#pragma unroll
  for (int o = 0; o < 3; ++o)
#pragma unroll
    for (int ci = 0; ci < 3; ++ci)
#pragma unroll
      for (int ky = 0; ky < 3; ++ky)
#pragma unroll
        for (int kx = 0; kx < 3; ++kx)
          wr[o][ci][ky][kx] = w2[((o * 3 + ci) * 3 + ky) * 3 + kx];
  __syncthreads();

  // conv2 over the z tile, 4-row strips
  int cc = threadIdx.x & 63;
  int rr0 = (threadIdx.x >> 6) * 4;
  float acc[4][3] = {};
#pragma unroll
  for (int ci = 0; ci < 3; ++ci)
#pragma unroll
    for (int kx = 0; kx < 3; ++kx) {
      float v[6];
#pragma unroll
      for (int i = 0; i < 6; ++i) v[i] = zs[ci][rr0 + i][cc + kx];
#pragma unroll
      for (int o = 0; o < 4; ++o)
#pragma unroll
        for (int ky = 0; ky < 3; ++ky) {
          float vv = v[o + ky];
#pragma unroll
          for (int co = 0; co < 3; ++co) acc[o][co] = fmaf(wr[co][ci][ky][kx], vv, acc[o][co]);
        }
    }

  if constexpr (FINAL) {
    float scale2[3], shift2[3];
#pragma unroll
    for (int c = 0; c < 3; ++c) {
      scale2[c] = hdr[6 + c];
      shift2[c] = hdr[9 + c];
    }
#pragma unroll
    for (int o = 0; o < 4; ++o) {
      int rr = rr0 + o;
#pragma unroll
      for (int co = 0; co < 3; ++co) {
        float y = fmaf(acc[o][co], scale2[co], shift2[co]);
        float v = y + xs[co][rr + 2][cc + 2];  // residual from halo-2 x tile
        dst[(((size_t)b * 3 + co) * HH + (h0 + rr)) * WW + (w0 + cc)] = ratf(v, A[co], Bq[co]);
      }
    }
  } else {
    float s[6] = {0.f, 0.f, 0.f, 0.f, 0.f, 0.f};
#pragma unroll
    for (int o = 0; o < 4; ++o)
#pragma unroll
      for (int co = 0; co < 3; ++co) {
        float y = acc[o][co];
        s[co] += y;
        s[3 + co] += y * y;
      }
    block_reduce6_store(s, dst + (size_t)bid * 6);
  }
}

extern "C" void kernel_launch(void* const* d_in, const int* in_sizes, int n_in,
                              void* d_out, int out_size, void* d_ws, size_t ws_size,
                              hipStream_t stream) {
  const float* x  = (const float*)d_in[0];
  const float* w1 = (const float*)d_in[1];
  const float* g1 = (const float*)d_in[2];
  const float* b1 = (const float*)d_in[3];
  const float* ar = (const float*)d_in[4];
  const float* br = (const float*)d_in[5];
  const float* ag = (const float*)d_in[6];
  const float* bg = (const float*)d_in[7];
  const float* ab = (const float*)d_in[8];
  const float* bb = (const float*)d_in[9];
  const float* w2 = (const float*)d_in[10];
  const float* g2 = (const float*)d_in[11];
  const float* b2 = (const float*)d_in[12];
  float* out = (float*)d_out;

  // partials scratch lives in d_out (fully overwritten by k_fused<true> last);
  // only the 48B scale/shift header needs d_ws.
  float* part1 = out;                        // NTILES*6 floats
  float* part2 = out + (size_t)NTILES * 6;   // NTILES*6 floats
  float* hdr = (float*)d_ws;                 // 12 floats

  k_stats1<<<dim3(NTILES), dim3(NTHR), 0, stream>>>(x, w1, part1);
  k_reduce<<<dim3(1), dim3(256), 0, stream>>>(part1, g1, b1, hdr);
  k_fused<false><<<dim3(NTILES), dim3(NTHR), 0, stream>>>(x, w1, w2, hdr, ar, br, ag, bg, ab, bb, part2);
  k_reduce<<<dim3(1), dim3(256), 0, stream>>>(part2, g2, b2, hdr + 6);
  k_fused<true><<<dim3(NTILES), dim3(NTHR), 0, stream>>>(x, w1, w2, hdr, ar, br, ag, bg, ab, bb, out);
}

// Round 3
// 849.364 us; speedup vs baseline: 1.0059x; 1.0059x over previous
//
#include <hip/hip_runtime.h>
#include <math.h>

#define HH 512
#define WW 512
#define NBATCH 64
#define TW 64
#define TH 16
#define NTILES (NBATCH * 8 * 32)  // 16384
#define NTHR 256

#define XT_H (TH + 4)  // 20  (halo 2)
#define XT_W (TW + 4)  // 68
#define ZT_H (TH + 2)  // 18
#define ZT_W (TW + 2)  // 66
#define X1_H (TH + 2)  // 18  (halo 1)
#define X1_W (TW + 2)  // 66

#define Y1_ELEMS ((size_t)NBATCH * 3 * HH * WW)  // 50331648
// fast path needs: y1 + part2 + hdr in d_ws
#define WS_FAST_BYTES ((Y1_ELEMS + (size_t)NTILES * 6 + 16) * 4)

// rational 'A': P(x)/(1+|Q(x)|), deg P=5, deg Q=4 no constant term
__device__ __forceinline__ float ratf(float v, const float* A, const float* B) {
  float p = fmaf(v, A[5], A[4]);
  p = fmaf(v, p, A[3]);
  p = fmaf(v, p, A[2]);
  p = fmaf(v, p, A[1]);
  p = fmaf(v, p, A[0]);
  float q = fmaf(v, B[3], B[2]);
  q = fmaf(v, q, B[1]);
  q = fmaf(v, q, B[0]);
  q *= v;
  float den = 1.0f + fabsf(q);
  return p * __builtin_amdgcn_rcpf(den);
}

__device__ __forceinline__ void block_reduce6_store(float s[6], float* __restrict__ dst) {
  __shared__ float red[4][6];
#pragma unroll
  for (int k = 0; k < 6; ++k) {
    float v = s[k];
#pragma unroll
    for (int off = 32; off; off >>= 1) v += __shfl_down(v, off, 64);
    s[k] = v;
  }
  int lane = threadIdx.x & 63, wv = threadIdx.x >> 6;
  if (lane == 0) {
#pragma unroll
    for (int k = 0; k < 6; ++k) red[wv][k] = s[k];
  }
  __syncthreads();
  if (threadIdx.x < 6) {
    dst[threadIdx.x] = red[0][threadIdx.x] + red[1][threadIdx.x] + red[2][threadIdx.x] + red[3][threadIdx.x];
  }
}

// ---------------- reduce partials -> scale/shift (6 floats) ----------------
__global__ __launch_bounds__(256) void k_reduce(const float* __restrict__ partials,
                                                const float* __restrict__ gamma,
                                                const float* __restrict__ beta,
                                                float* __restrict__ out6) {
  double s[6] = {0, 0, 0, 0, 0, 0};
  for (int j = threadIdx.x; j < NTILES; j += 256) {
    const float* p = partials + (size_t)j * 6;
#pragma unroll
    for (int k = 0; k < 6; ++k) s[k] += (double)p[k];
  }
  __shared__ double red[256];
  __shared__ double tot[6];
  for (int k = 0; k < 6; ++k) {
    red[threadIdx.x] = s[k];
    __syncthreads();
    for (int off = 128; off; off >>= 1) {
      if (threadIdx.x < off) red[threadIdx.x] += red[threadIdx.x + off];
      __syncthreads();
    }
    if (threadIdx.x == 0) tot[k] = red[0];
    __syncthreads();
  }
  if (threadIdx.x < 3) {
    int c = threadIdx.x;
    double N = 16777216.0;  // 64*512*512
    double mean = tot[c] / N;
    double var = tot[3 + c] / N - mean * mean;
    double sc = (double)gamma[c] / sqrt(var + 1e-5);
    double sh = (double)beta[c] - mean * sc;
    out6[c] = (float)sc;
    out6[3 + c] = (float)sh;
  }
}

// ======================= FAST PATH (y1 materialized) =======================

// P1: conv1 -> y1 (global) + stats1 partials
__global__ __launch_bounds__(NTHR) void k_conv1(const float* __restrict__ x,
                                                const float* __restrict__ w1,
                                                float* __restrict__ y1,
                                                float* __restrict__ partials) {
  __shared__ float xs[3][X1_H][X1_W];
  int bid = blockIdx.x;
  int tx = bid & 7, ty = (bid >> 3) & 31, b = bid >> 8;
  int h0 = ty * TH, w0 = tx * TW;
  int lane = threadIdx.x & 63, grp = threadIdx.x >> 6;

  // divmod-free staging: group g covers rows g, g+4, ...; lane = col, lanes 0,1 do cols 64,65
#pragma unroll
  for (int c = 0; c < 3; ++c) {
    const float* xp = x + ((size_t)b * 3 + c) * HH * WW;
    for (int r = grp; r < X1_H; r += 4) {
      int gh = h0 - 1 + r;
      int gw = w0 - 1 + lane;
      float v = 0.f;
      if ((unsigned)gh < HH && (unsigned)gw < WW) v = xp[(size_t)gh * WW + gw];
      xs[c][r][lane] = v;
      if (lane < 2) {
        int gw2 = w0 + 63 + lane;
        float v2 = 0.f;
        if ((unsigned)gh < HH && (unsigned)gw2 < WW) v2 = xp[(size_t)gh * WW + gw2];
        xs[c][r][64 + lane] = v2;
      }
    }
  }
  float wr[3][3][3][3];
#pragma unroll
  for (int o = 0; o < 3; ++o)
#pragma unroll
    for (int ci = 0; ci < 3; ++ci)
#pragma unroll
      for (int ky = 0; ky < 3; ++ky)
#pragma unroll
        for (int kx = 0; kx < 3; ++kx)
          wr[o][ci][ky][kx] = w1[((o * 3 + ci) * 3 + ky) * 3 + kx];
  __syncthreads();

  int cc = lane;
  int rr0 = grp * 4;  // 4-row strip
  float acc[4][3] = {};
#pragma unroll
  for (int ci = 0; ci < 3; ++ci)
#pragma unroll
    for (int kx = 0; kx < 3; ++kx) {
      float v[6];
#pragma unroll
      for (int i = 0; i < 6; ++i) v[i] = xs[ci][rr0 + i][cc + kx];
#pragma unroll
      for (int o = 0; o < 4; ++o)
#pragma unroll
        for (int ky = 0; ky < 3; ++ky) {
          float vv = v[o + ky];
#pragma unroll
          for (int co = 0; co < 3; ++co) acc[o][co] = fmaf(wr[co][ci][ky][kx], vv, acc[o][co]);
        }
    }
  float s[6] = {0.f, 0.f, 0.f, 0.f, 0.f, 0.f};
#pragma unroll
  for (int o = 0; o < 4; ++o)
#pragma unroll
    for (int co = 0; co < 3; ++co) {
      float y = acc[o][co];
      y1[(((size_t)b * 3 + co) * HH + (h0 + rr0 + o)) * WW + (w0 + cc)] = y;
      s[co] += y;
      s[3 + co] += y * y;
    }
  block_reduce6_store(s, partials + (size_t)bid * 6);
}

// P2: y1 -> z (LDS, pointwise bn1+rational) -> conv2 -> u (global) + stats2 partials
__global__ __launch_bounds__(NTHR) void k_conv2s(const float* __restrict__ y1,
                                                 const float* __restrict__ w2,
                                                 const float* __restrict__ hdr,
                                                 const float* __restrict__ ar, const float* __restrict__ br,
                                                 const float* __restrict__ ag, const float* __restrict__ bg,
                                                 const float* __restrict__ ab_, const float* __restrict__ bb,
                                                 float* __restrict__ u,
                                                 float* __restrict__ partials) {
  __shared__ float zs[3][ZT_H][ZT_W];
  int bid = blockIdx.x;
  int tx = bid & 7, ty = (bid >> 3) & 31, b = bid >> 8;
  int h0 = ty * TH, w0 = tx * TW;
  int lane = threadIdx.x & 63, grp = threadIdx.x >> 6;

  float sc1[3], sh1[3];
#pragma unroll
  for (int c = 0; c < 3; ++c) {
    sc1[c] = hdr[c];
    sh1[c] = hdr[3 + c];
  }
  float A[3][6], Bq[3][4];
#pragma unroll
  for (int i = 0; i < 6; ++i) { A[0][i] = ar[i]; A[1][i] = ag[i]; A[2][i] = ab_[i]; }
#pragma unroll
  for (int i = 0; i < 4; ++i) { Bq[0][i] = br[i]; Bq[1][i] = bg[i]; Bq[2][i] = bb[i]; }

  // staged transform: z = rational(bn1(y1)), zeros outside image (SAME padding)
#pragma unroll
  for (int c = 0; c < 3; ++c) {
    const float* yp = y1 + ((size_t)b * 3 + c) * HH * WW;
    for (int r = grp; r < ZT_H; r += 4) {
      int gh = h0 - 1 + r;
      int gw = w0 - 1 + lane;
      float z = 0.f;
      if ((unsigned)gh < HH && (unsigned)gw < WW)
        z = ratf(fmaf(yp[(size_t)gh * WW + gw], sc1[c], sh1[c]), A[c], Bq[c]);
      zs[c][r][lane] = z;
      if (lane < 2) {
        int gw2 = w0 + 63 + lane;
        float z2 = 0.f;
        if ((unsigned)gh < HH && (unsigned)gw2 < WW)
          z2 = ratf(fmaf(yp[(size_t)gh * WW + gw2], sc1[c], sh1[c]), A[c], Bq[c]);
        zs[c][r][64 + lane] = z2;
      }
    }
  }
  float wr[3][3][3][3];
#pragma unroll
  for (int o = 0; o < 3; ++o)
#pragma unroll
    for (int ci = 0; ci < 3; ++ci)
#pragma unroll
      for (int ky = 0; ky < 3; ++ky)
#pragma unroll
        for (int kx = 0; kx < 3; ++kx)
          wr[o][ci][ky][kx] = w2[((o * 3 + ci) * 3 + ky) * 3 + kx];
  __syncthreads();

  int cc = lane;
  int rr0 = grp * 4;
  float acc[4][3] = {};
#pragma unroll
  for (int ci = 0; ci < 3; ++ci)
#pragma unroll
    for (int kx = 0; kx < 3; ++kx) {
      float v[6];
#pragma unroll
      for (int i = 0; i < 6; ++i) v[i] = zs[ci][rr0 + i][cc + kx];
#pragma unroll
      for (int o = 0; o < 4; ++o)
#pragma unroll
        for (int ky = 0; ky < 3; ++ky) {
          float vv = v[o + ky];
#pragma unroll
          for (int co = 0; co < 3; ++co) acc[o][co] = fmaf(wr[co][ci][ky][kx], vv, acc[o][co]);
        }
    }
  float s[6] = {0.f, 0.f, 0.f, 0.f, 0.f, 0.f};
#pragma unroll
  for (int o = 0; o < 4; ++o)
#pragma unroll
    for (int co = 0; co < 3; ++co) {
      float y = acc[o][co];
      u[(((size_t)b * 3 + co) * HH + (h0 + rr0 + o)) * WW + (w0 + cc)] = y;
      s[co] += y;
      s[3 + co] += y * y;
    }
  block_reduce6_store(s, partials + (size_t)bid * 6);
}

// P3: pointwise bn2 + residual + rational, in-place on u (=d_out), float4
__global__ __launch_bounds__(NTHR) void k_pointwise(float* __restrict__ u,
                                                    const float* __restrict__ x,
                                                    const float* __restrict__ hdr,
                                                    const float* __restrict__ ar, const float* __restrict__ br,
                                                    const float* __restrict__ ag, const float* __restrict__ bg,
                                                    const float* __restrict__ ab_, const float* __restrict__ bb) {
  int plane = blockIdx.y;           // 0..191 = b*3+c
  int c = plane % 3;
  const float* Ap = (c == 0) ? ar : ((c == 1) ? ag : ab_);
  const float* Bp = (c == 0) ? br : ((c == 1) ? bg : bb);
  float A[6], Bc[4];
#pragma unroll
  for (int i = 0; i < 6; ++i) A[i] = Ap[i];
#pragma unroll
  for (int i = 0; i < 4; ++i) Bc[i] = Bp[i];
  float sc2 = hdr[6 + c], sh2 = hdr[9 + c];

  size_t base = (size_t)plane * (HH * WW) + (size_t)blockIdx.x * 4096;
  const float4* xv = (const float4*)(x + base);
  float4* uv = (float4*)(u + base);
#pragma unroll
  for (int k = 0; k < 4; ++k) {
    int i = k * NTHR + threadIdx.x;
    float4 uu = uv[i];
    float4 xx = xv[i];
    float4 o;
    o.x = ratf(fmaf(uu.x, sc2, sh2) + xx.x, A, Bc);
    o.y = ratf(fmaf(uu.y, sc2, sh2) + xx.y, A, Bc);
    o.z = ratf(fmaf(uu.z, sc2, sh2) + xx.z, A, Bc);
    o.w = ratf(fmaf(uu.w, sc2, sh2) + xx.w, A, Bc);
    uv[i] = o;
  }
}

// ======================= FALLBACK PATH (R2, proven) ========================

__global__ __launch_bounds__(NTHR) void k_stats1(const float* __restrict__ x,
                                                 const float* __restrict__ w1,
                                                 float* __restrict__ partials) {
  __shared__ float xs[3][X1_H][X1_W];
  int bid = blockIdx.x;
  int tx = bid & 7, ty = (bid >> 3) & 31, b = bid >> 8;
  int h0 = ty * TH, w0 = tx * TW;

  const int NE = 3 * X1_H * X1_W;
  for (int i = threadIdx.x; i < NE; i += NTHR) {
    int c = i / (X1_H * X1_W);
    int rem = i - c * (X1_H * X1_W);
    int r = rem / X1_W, cc = rem - r * X1_W;
    int gh = h0 - 1 + r, gw = w0 - 1 + cc;
    float v = 0.f;
    if ((unsigned)gh < HH && (unsigned)gw < WW)
      v = x[(((size_t)b * 3 + c) * HH + gh) * WW + gw];
    xs[c][r][cc] = v;
  }
  float wr[3][3][3][3];
#pragma unroll
  for (int o = 0; o < 3; ++o)
#pragma unroll
    for (int ci = 0; ci < 3; ++ci)
#pragma unroll
      for (int ky = 0; ky < 3; ++ky)
#pragma unroll
        for (int kx = 0; kx < 3; ++kx)
          wr[o][ci][ky][kx] = w1[((o * 3 + ci) * 3 + ky) * 3 + kx];
  __syncthreads();

  int cc = threadIdx.x & 63;
  int rr0 = (threadIdx.x >> 6) * 4;
  float acc[4][3] = {};
#pragma unroll
  for (int ci = 0; ci < 3; ++ci)
#pragma unroll
    for (int kx = 0; kx < 3; ++kx) {
      float v[6];
#pragma unroll
      for (int i = 0; i < 6; ++i) v[i] = xs[ci][rr0 + i][cc + kx];
#pragma unroll
      for (int o = 0; o < 4; ++o)
#pragma unroll
        for (int ky = 0; ky < 3; ++ky) {
          float vv = v[o + ky];
#pragma unroll
          for (int co = 0; co < 3; ++co) acc[o][co] = fmaf(wr[co][ci][ky][kx], vv, acc[o][co]);
        }
    }
  float s[6] = {0.f, 0.f, 0.f, 0.f, 0.f, 0.f};
#pragma unroll
  for (int o = 0; o < 4; ++o)
#pragma unroll
    for (int co = 0; co < 3; ++co) {
      float y = acc[o][co];
      s[co] += y;
      s[3 + co] += y * y;
    }
  block_reduce6_store(s, partials + (size_t)bid * 6);
}

template <bool FINAL>
__global__ __launch_bounds__(NTHR) void k_fused(const float* __restrict__ x,
                                                const float* __restrict__ w1,
                                                const float* __restrict__ w2,
                                                const float* __restrict__ hdr,
                                                const float* __restrict__ ar, const float* __restrict__ br,
                                                const float* __restrict__ ag, const float* __restrict__ bg,
                                                const float* __restrict__ ab_, const float* __restrict__ bb,
                                                float* __restrict__ dst) {
  __shared__ float xs[3][XT_H][XT_W];
  __shared__ float zs[3][ZT_H][ZT_W];
  int bid = blockIdx.x;
  int tx = bid & 7, ty = (bid >> 3) & 31, b = bid >> 8;
  int h0 = ty * TH, w0 = tx * TW;

  const int NE = 3 * XT_H * XT_W;
  for (int i = threadIdx.x; i < NE; i += NTHR) {
    int c = i / (XT_H * XT_W);
    int rem = i - c * (XT_H * XT_W);
    int r = rem / XT_W, cc = rem - r * XT_W;
    int gh = h0 - 2 + r, gw = w0 - 2 + cc;
    float v = 0.f;
    if ((unsigned)gh < HH && (unsigned)gw < WW)
      v = x[(((size_t)b * 3 + c) * HH + gh) * WW + gw];
    xs[c][r][cc] = v;
  }

  float scale1[3], shift1[3];
#pragma unroll
  for (int c = 0; c < 3; ++c) {
    scale1[c] = hdr[c];
    shift1[c] = hdr[3 + c];
  }
  float A[3][6], Bq[3][4];
#pragma unroll
  for (int i = 0; i < 6; ++i) { A[0][i] = ar[i]; A[1][i] = ag[i]; A[2][i] = ab_[i]; }
#pragma unroll
  for (int i = 0; i < 4; ++i) { Bq[0][i] = br[i]; Bq[1][i] = bg[i]; Bq[2][i] = bb[i]; }

  float wr[3][3][3][3];
#pragma unroll
  for (int o = 0; o < 3; ++o)
#pragma unroll
    for (int ci = 0; ci < 3; ++ci)
#pragma unroll
      for (int ky = 0; ky < 3; ++ky)
#pragma unroll
        for (int kx = 0; kx < 3; ++kx)
          wr[o][ci][ky][kx] = w1[((o * 3 + ci) * 3 + ky) * 3 + kx];
  __syncthreads();

  for (int i = threadIdx.x; i < ZT_H * ZT_W; i += NTHR) {
    int r = i / ZT_W, cc = i - r * ZT_W;
    int gh = h0 - 1 + r, gw = w0 - 1 + cc;
    float z0 = 0.f, z1 = 0.f, z2 = 0.f;
    if ((unsigned)gh < HH && (unsigned)gw < WW) {
      float a0 = 0.f, a1 = 0.f, a2 = 0.f;
#pragma unroll
      for (int ci = 0; ci < 3; ++ci)
#pragma unroll
        for (int ky = 0; ky < 3; ++ky)
#pragma unroll
          for (int kx = 0; kx < 3; ++kx) {
            float v = xs[ci][r + ky][cc + kx];
            a0 = fmaf(wr[0][ci][ky][kx], v, a0);
            a1 = fmaf(wr[1][ci][ky][kx], v, a1);
            a2 = fmaf(wr[2][ci][ky][kx], v, a2);
          }
      z0 = ratf(fmaf(a0, scale1[0], shift1[0]), A[0], Bq[0]);
      z1 = ratf(fmaf(a1, scale1[1], shift1[1]), A[1], Bq[1]);
      z2 = ratf(fmaf(a2, scale1[2], shift1[2]), A[2], Bq[2]);
    }
    zs[0][r][cc] = z0;
    zs[1][r][cc] = z1;
    zs[2][r][cc] = z2;
  }

#pragma unroll
  for (int o = 0; o < 3; ++o)
#pragma unroll
    for (int ci = 0; ci < 3; ++ci)
#pragma unroll
      for (int ky = 0; ky < 3; ++ky)
#pragma unroll
        for (int kx = 0; kx < 3; ++kx)
          wr[o][ci][ky][kx] = w2[((o * 3 + ci) * 3 + ky) * 3 + kx];
  __syncthreads();

  int cc = threadIdx.x & 63;
  int rr0 = (threadIdx.x >> 6) * 4;
  float acc[4][3] = {};
#pragma unroll
  for (int ci = 0; ci < 3; ++ci)
#pragma unroll
    for (int kx = 0; kx < 3; ++kx) {
      float v[6];
#pragma unroll
      for (int i = 0; i < 6; ++i) v[i] = zs[ci][rr0 + i][cc + kx];
#pragma unroll
      for (int o = 0; o < 4; ++o)
#pragma unroll
        for (int ky = 0; ky < 3; ++ky) {
          float vv = v[o + ky];
#pragma unroll
          for (int co = 0; co < 3; ++co) acc[o][co] = fmaf(wr[co][ci][ky][kx], vv, acc[o][co]);
        }
    }

  if constexpr (FINAL) {
    float scale2[3], shift2[3];
#pragma unroll
    for (int c = 0; c < 3; ++c) {
      scale2[c] = hdr[6 + c];
      shift2[c] = hdr[9 + c];
    }
#pragma unroll
    for (int o = 0; o < 4; ++o) {
      int rr = rr0 + o;
#pragma unroll
      for (int co = 0; co < 3; ++co) {
        float y = fmaf(acc[o][co], scale2[co], shift2[co]);
        float v = y + xs[co][rr + 2][cc + 2];
        dst[(((size_t)b * 3 + co) * HH + (h0 + rr)) * WW + (w0 + cc)] = ratf(v, A[co], Bq[co]);
      }
    }
  } else {
    float s[6] = {0.f, 0.f, 0.f, 0.f, 0.f, 0.f};
#pragma unroll
    for (int o = 0; o < 4; ++o)
#pragma unroll
      for (int co = 0; co < 3; ++co) {
        float y = acc[o][co];
        s[co] += y;
        s[3 + co] += y * y;
      }
    block_reduce6_store(s, dst + (size_t)bid * 6);
  }
}

extern "C" void kernel_launch(void* const* d_in, const int* in_sizes, int n_in,
                              void* d_out, int out_size, void* d_ws, size_t ws_size,
                              hipStream_t stream) {
  const float* x  = (const float*)d_in[0];
  const float* w1 = (const float*)d_in[1];
  const float* g1 = (const float*)d_in[2];
  const float* b1 = (const float*)d_in[3];
  const float* ar = (const float*)d_in[4];
  const float* br = (const float*)d_in[5];
  const float* ag = (const float*)d_in[6];
  const float* bg = (const float*)d_in[7];
  const float* ab = (const float*)d_in[8];
  const float* bb = (const float*)d_in[9];
  const float* w2 = (const float*)d_in[10];
  const float* g2 = (const float*)d_in[11];
  const float* b2 = (const float*)d_in[12];
  float* out = (float*)d_out;

  if (ws_size >= WS_FAST_BYTES) {
    // fast path: y1 materialized in d_ws; u materialized in d_out
    float* y1   = (float*)d_ws;
    float* part2 = (float*)d_ws + Y1_ELEMS;
    float* hdr  = part2 + (size_t)NTILES * 6;     // 12 floats
    float* part1 = out;                            // consumed before u is written

    k_conv1<<<dim3(NTILES), dim3(NTHR), 0, stream>>>(x, w1, y1, part1);
    k_reduce<<<dim3(1), dim3(256), 0, stream>>>(part1, g1, b1, hdr);
    k_conv2s<<<dim3(NTILES), dim3(NTHR), 0, stream>>>(y1, w2, hdr, ar, br, ag, bg, ab, bb, out, part2);
    k_reduce<<<dim3(1), dim3(256), 0, stream>>>(part2, g2, b2, hdr + 6);
    k_pointwise<<<dim3(64, 192), dim3(NTHR), 0, stream>>>(out, x, hdr, ar, br, ag, bg, ab, bb);
  } else {
    // fallback: recompute path (R2)
    float* part1 = out;
    float* part2 = out + (size_t)NTILES * 6;
    float* hdr = (float*)d_ws;

    k_stats1<<<dim3(NTILES), dim3(NTHR), 0, stream>>>(x, w1, part1);
    k_reduce<<<dim3(1), dim3(256), 0, stream>>>(part1, g1, b1, hdr);
    k_fused<false><<<dim3(NTILES), dim3(NTHR), 0, stream>>>(x, w1, w2, hdr, ar, br, ag, bg, ab, bb, part2);
    k_reduce<<<dim3(1), dim3(256), 0, stream>>>(part2, g2, b2, hdr + 6);
    k_fused<true><<<dim3(NTILES), dim3(NTHR), 0, stream>>>(x, w1, w2, hdr, ar, br, ag, bg, ab, bb, out);
  }
}